// Round 2
// baseline (778.068 us; speedup 1.0000x reference)
//
#include <hip/hip_runtime.h>
#include <hip/hip_bf16.h>

typedef __bf16 bf16x8 __attribute__((ext_vector_type(8)));
typedef __bf16 bf16x4 __attribute__((ext_vector_type(4)));
typedef float  f32x4  __attribute__((ext_vector_type(4)));
typedef float  f32x16 __attribute__((ext_vector_type(16)));

#define B_    64
#define CIN   64
#define HIN   64
#define WIN   64
#define COUT  128
#define HO    62
#define WO    62
#define NPIX  (B_*HO*WO)        /* 246016 = 3844*64 exactly */
#define NITER 10                /* register rounds; +1 final matvec = 11 total */

// Pin a matrix fragment into AGPRs (used by conv only now).
#define PIN_A(x) asm volatile("" : "+a"(x))
#define PIN_V(x) asm volatile("" : "+v"(x))

// ---------------------------------------------------------------------------
// prep_w: W_ff -> wt[tap][o][c] bf16 ;
//         W_rec -> wrp: NEGATED, pre-permuted per-lane A-fragment table.
// wrp[((mt*4+kt)*64 + lane)*8 + e] = -wrec[m][ch],
//   m  = mt*16 + (lane&15)
//   ch = kt*16 + 64*(e>>2) + (lane>>4)*4 + (e&3)   (k-slot permutation)
// Total 32 frags x 64 lanes x 16B = 32 KB; identical for every wave, so
// iterate keeps ONE LDS copy per block instead of 128 AGPRs per wave.
// ---------------------------------------------------------------------------
__global__ void prep_w_kernel(const float* __restrict__ wff,
                              const float* __restrict__ wrec,
                              __bf16* __restrict__ wt,
                              __bf16* __restrict__ wrp) {
  int i = blockIdx.x * 256 + threadIdx.x;
  const int NW = 9 * COUT * CIN;            // 73728
  if (i < NW) {
    int tap = i / (COUT * CIN);
    int rem = i % (COUT * CIN);
    int o = rem >> 6;
    int c = rem & 63;
    int kh = tap / 3, kw = tap % 3;
    wt[i] = (__bf16)wff[((o * CIN + c) * 3 + kh) * 3 + kw];
  } else {
    int j = i - NW;                         // 0..16383
    if (j < 32 * 64 * 8) {
      int e    = j & 7;
      int lane = (j >> 3) & 63;
      int fk   = j >> 9;                    // mt*4 + kt
      int mt = fk >> 2, kt = fk & 3;
      int m    = mt * 16 + (lane & 15);
      int quad = lane >> 4;
      int ch   = kt * 16 + ((e >> 2) << 6) + quad * 4 + (e & 3);
      wrp[j] = (__bf16)(-wrec[m * COUT + ch]);
    }
  }
}

// ---------------------------------------------------------------------------
// prep_x: x NCHW fp32 -> bf16, layout [b][h][c>>3][w][c&7]
// ---------------------------------------------------------------------------
__global__ void prep_x_kernel(const float* __restrict__ x,
                              __bf16* __restrict__ xh) {
  __shared__ float t[64][65];
  int tid = threadIdx.x;
  int b = blockIdx.x >> 6;
  int h = blockIdx.x & 63;
#pragma unroll
  for (int it = 0; it < 16; ++it) {
    int c = it * 4 + (tid >> 6);
    int w = tid & 63;
    t[c][w] = x[(((size_t)(b * 64 + c)) * 64 + h) * 64 + w];
  }
  __syncthreads();
  size_t rowbase = (size_t)blockIdx.x * 4096;
#pragma unroll
  for (int it = 0; it < 16; ++it) {
    int j = it * 256 + tid;
    int c8  = j & 7;
    int w   = (j >> 3) & 63;
    int grp = j >> 9;
    xh[rowbase + j] = (__bf16)t[grp * 8 + c8][w];
  }
}

// ---------------------------------------------------------------------------
// conv: persistent-weight implicit GEMM, 32x32x16 bf16 MFMA.
// Wf (144 regs) pinned into AGPRs -> zero weight traffic in the nt loop.
// ---------------------------------------------------------------------------
__global__ __launch_bounds__(256, 2) void conv_kernel(
    const __bf16* __restrict__ xh, const __bf16* __restrict__ wt,
    float* __restrict__ u0) {
  // layout [row 6][grp 8][w 64][c8 8] = 24576 el = 48KB, flat == global order
  __shared__ __align__(16) __bf16 xs[6 * 8 * 64 * 8];
  int tid  = threadIdx.x;
  int lane = tid & 63;
  int wv   = tid >> 6;                      // 0..3 : c_out slice
  int hg   = blockIdx.x;                    // 0..15 : output-row group (4 rows)
  int b    = blockIdx.y;

  // ---- stage 6 input rows (hg*4 .. hg*4+5, clamped) ----
#pragma unroll
  for (int i = 0; i < 12; ++i) {
    int chunk = wv * 12 + i;                // 0..47
    int row = chunk >> 3;
    int part = chunk & 7;
    int row_src = hg * 4 + row;
    if (row_src > 63) row_src = 63;
    const __bf16* g = xh + ((size_t)(b * 64 + row_src)) * 4096 + part * 512 + lane * 8;
    __bf16* l = xs + chunk * 512;
    __builtin_amdgcn_global_load_lds(
        (const __attribute__((address_space(1))) void*)g,
        (__attribute__((address_space(3))) void*)l, 16, 0, 0);
  }

  // ---- this wave's full weight set -> AGPRs (loaded once, resident) ----
  int m31 = lane & 31;
  int khalf = lane >> 5;                    // A[m][k]: m=lane&31, k=khalf*8+j
  bf16x8 Wf[36];
#pragma unroll
  for (int tap = 0; tap < 9; ++tap)
#pragma unroll
    for (int k4 = 0; k4 < 4; ++k4)
      Wf[tap * 4 + k4] = *(const bf16x8*)
          &wt[((size_t)tap * COUT + wv * 32 + m31) * CIN + k4 * 16 + khalf * 8];
#pragma unroll
  for (int i = 0; i < 36; ++i) PIN_A(Wf[i]);

  __syncthreads();

  // ---- 8 n-tiles of 32 pixels ----
#pragma unroll 1
  for (int nt = 0; nt < 8; ++nt) {
    int px = nt * 32 + m31;                 // local pixel 0..255 (248 valid)
    int r = (px >= 62) + (px >= 124) + (px >= 186) + (px >= 248);
    if (r > 3) r = 3;
    int wcol = px - r * 62;
    if (wcol > 61) wcol = 61;
    int orow = hg * 4 + r;
    bool valid = (px < 248) && (orow < 62);
    const char* lbase = (const char*)xs + (((r * 8 + khalf) * 64 + wcol) << 4);

    f32x16 acc0, acc1;
#pragma unroll
    for (int q = 0; q < 16; ++q) { acc0[q] = 0.f; acc1[q] = 0.f; }

#pragma unroll
    for (int tap = 0; tap < 9; ++tap) {
      int kh = tap / 3, kw = tap % 3;
#pragma unroll
      for (int k4 = 0; k4 < 4; ++k4) {
        bf16x8 Bf = *(const bf16x8*)(lbase + kh * 8192 + k4 * 2048 + kw * 16);
        int idx = tap * 4 + k4;
        if (idx & 1) acc1 = __builtin_amdgcn_mfma_f32_32x32x16_bf16(Wf[idx], Bf, acc1, 0, 0, 0);
        else         acc0 = __builtin_amdgcn_mfma_f32_32x32x16_bf16(Wf[idx], Bf, acc0, 0, 0, 0);
      }
    }
    if (valid) {
      size_t pix = ((size_t)b * HO + orow) * WO + wcol;
      // C/D layout 32x32: col=lane&31, row=(reg&3)+8*(reg>>2)+4*khalf
      float* up = u0 + pix * COUT + wv * 32 + khalf * 4;
#pragma unroll
      for (int g4 = 0; g4 < 4; ++g4) {
        f32x4 v;
#pragma unroll
        for (int q = 0; q < 4; ++q) v[q] = acc0[g4 * 4 + q] + acc1[g4 * 4 + q];
        *(f32x4*)&up[g4 * 8] = v;
      }
    }
  }
}

// ---------------------------------------------------------------------------
// iterate: 11 undamped Picard matvecs. Wave owns M=128 x N=16 pixels.
// R1 post-mortem: pinning -Wr in 128 AGPRs capped occupancy at 2 waves/SIMD
// and the kernel is latency-bound (all pipes <25%). The A-fragments are
// IDENTICAL for every wave (lane-dependent only), so keep ONE 32 KB copy in
// LDS per block and ds_read_b128 each fragment at use. Register budget drops
// to ~100 -> __launch_bounds__(256,4) = 4 waves/SIMD, 2x occupancy.
// LDS reads are lane-stride-16B contiguous (conflict-free), wave-uniform
// base + immediate offsets. Repack stays in-register (k-permutation).
// ---------------------------------------------------------------------------
__global__ __launch_bounds__(256, 4) void iterate_kernel(
    const float* __restrict__ u0, const __bf16* __restrict__ wrp,
    const float* __restrict__ thr, float* __restrict__ out) {
  __shared__ __align__(16) __bf16 wrl[32 * 64 * 8];   // 32 KB shared A-table
  int tid = threadIdx.x;
  int lane = tid & 63, wv = tid >> 6;
  int l15 = lane & 15, quad = lane >> 4;
  size_t p = (size_t)blockIdx.x * 64 + wv * 16 + l15; // this lane's pixel
  int pb = (int)(p / (HO * WO));            // batch  (for NCHW store)
  int pr = (int)(p % (HO * WO));            // h*62+w

  // ---- stage wrp -> LDS (8 x 16B per thread, linear both sides) ----
#pragma unroll
  for (int i = 0; i < 8; ++i) {
    const __bf16* g = wrp + (size_t)(i * 256 + tid) * 8;
    __bf16* l = wrl + (i * 256 + tid) * 8;
    __builtin_amdgcn_global_load_lds(
        (const __attribute__((address_space(1))) void*)g,
        (__attribute__((address_space(3))) void*)l, 16, 0, 0);
  }

  // u0 - thr fragments (C-layout), VGPR-resident
  f32x4 u0f[8];
#pragma unroll
  for (int mt = 0; mt < 8; ++mt) {
    f32x4 u = *(const f32x4*)&u0[p * COUT + mt * 16 + quad * 4];
    f32x4 t = *(const f32x4*)&thr[mt * 16 + quad * 4];
    u0f[mt] = u - t;
  }
#pragma unroll
  for (int mt = 0; mt < 8; ++mt) PIN_V(u0f[mt]);

  // acc starts as u0-thr so the first repack yields a_0 = relu(u0-thr)
  f32x4 acc[8];
#pragma unroll
  for (int mt = 0; mt < 8; ++mt) acc[mt] = u0f[mt];

  __syncthreads();                          // wrl ready (vmcnt drained here)

  const __bf16* afrag = &wrl[(size_t)lane * 8];   // + fk*1024B immediates

  bf16x8 Bf[4];
#pragma unroll 1
  for (int it = 0; it < NITER; ++it) {
    // repack: B-slot (kt, q, e) <- relu(acc channel kt*16+64*(e>>2)+q*4+(e&3))
    //         = relu(acc[kt + 4*(e>>2)][e&3])   (purely lane-local)
#pragma unroll
    for (int kt = 0; kt < 4; ++kt) {
      bf16x8 v;
#pragma unroll
      for (int e = 0; e < 4; ++e) v[e]     = (__bf16)fmaxf(acc[kt][e],     0.f);
#pragma unroll
      for (int e = 0; e < 4; ++e) v[e + 4] = (__bf16)fmaxf(acc[kt + 4][e], 0.f);
      Bf[kt] = v;
    }
#pragma unroll
    for (int mt = 0; mt < 8; ++mt) {
      f32x4 a = u0f[mt];                    // acc init = u0-thr; Wr negated
#pragma unroll
      for (int kt = 0; kt < 4; ++kt) {
        bf16x8 Af = *(const bf16x8*)(afrag + (size_t)(mt * 4 + kt) * 512);
        a = __builtin_amdgcn_mfma_f32_16x16x32_bf16(Af, Bf[kt], a, 0, 0, 0);
      }
      acc[mt] = a;
    }
  }
  // final matvec -> relu -> NCHW global store
  {
#pragma unroll
    for (int kt = 0; kt < 4; ++kt) {
      bf16x8 v;
#pragma unroll
      for (int e = 0; e < 4; ++e) v[e]     = (__bf16)fmaxf(acc[kt][e],     0.f);
#pragma unroll
      for (int e = 0; e < 4; ++e) v[e + 4] = (__bf16)fmaxf(acc[kt + 4][e], 0.f);
      Bf[kt] = v;
    }
#pragma unroll
    for (int mt = 0; mt < 8; ++mt) {
      f32x4 a = u0f[mt];
#pragma unroll
      for (int kt = 0; kt < 4; ++kt) {
        bf16x8 Af = *(const bf16x8*)(afrag + (size_t)(mt * 4 + kt) * 512);
        a = __builtin_amdgcn_mfma_f32_16x16x32_bf16(Af, Bf[kt], a, 0, 0, 0);
      }
#pragma unroll
      for (int r = 0; r < 4; ++r) {
        int ch = mt * 16 + quad * 4 + r;
        out[((size_t)pb * COUT + ch) * (HO * WO) + pr] = fmaxf(a[r], 0.f);
      }
    }
  }
}

// ---------------------------------------------------------------------------
extern "C" void kernel_launch(void* const* d_in, const int* in_sizes, int n_in,
                              void* d_out, int out_size, void* d_ws, size_t ws_size,
                              hipStream_t stream) {
  const float* x    = (const float*)d_in[0];   // (64,64,64,64)
  const float* wff  = (const float*)d_in[1];   // (128,64,3,3)
  const float* wrec = (const float*)d_in[2];   // (128,128,1,1)
  const float* thr  = (const float*)d_in[3];   // (128,)
  float* out = (float*)d_out;                  // (64,128,62,62)

  char* ws = (char*)d_ws;
  size_t off = 0;
  float*  u0 = (float*)(ws + off);  off += (size_t)NPIX * COUT * 4;          // 126 MB
  __bf16* xh = (__bf16*)(ws + off); off += (size_t)B_ * HIN * WIN * CIN * 2; // 33.6 MB
  __bf16* wt = (__bf16*)(ws + off); off += (size_t)9 * COUT * CIN * 2;       // 147 KB
  __bf16* wrp = (__bf16*)(ws + off); off += (size_t)32 * 64 * 8 * 2;         // 32 KB

  prep_w_kernel<<<352, 256, 0, stream>>>(wff, wrec, wt, wrp);
  prep_x_kernel<<<B_ * HIN, 256, 0, stream>>>(x, xh);
  conv_kernel<<<dim3(16, B_), 256, 0, stream>>>(xh, wt, u0);
  iterate_kernel<<<NPIX / 64, 256, 0, stream>>>(u0, wrp, thr, out);
}

// Round 3
// 521.130 us; speedup vs baseline: 1.4930x; 1.4930x over previous
//
#include <hip/hip_runtime.h>
#include <hip/hip_bf16.h>

typedef __bf16 bf16x8 __attribute__((ext_vector_type(8)));
typedef __bf16 bf16x4 __attribute__((ext_vector_type(4)));
typedef float  f32x4  __attribute__((ext_vector_type(4)));
typedef float  f32x16 __attribute__((ext_vector_type(16)));

#define B_    64
#define CIN   64
#define HIN   64
#define WIN   64
#define COUT  128
#define HO    62
#define WO    62
#define NPIX  (B_*HO*WO)        /* 246016 = 3844*64 exactly */
#define NITER 10                /* register rounds; +1 final matvec = 11 total */

// Pin a matrix fragment into AGPRs (used by conv only now).
#define PIN_A(x) asm volatile("" : "+a"(x))
#define PIN_V(x) asm volatile("" : "+v"(x))

// ---------------------------------------------------------------------------
// prep_w: W_ff -> wt[tap][o][c] bf16 ;
//         W_rec -> wrp: NEGATED, pre-permuted per-lane A-fragment table.
// wrp[((mt*4+kt)*64 + lane)*8 + e] = -wrec[m][ch],
//   m  = mt*16 + (lane&15)
//   ch = kt*16 + 64*(e>>2) + (lane>>4)*4 + (e&3)   (k-slot permutation)
// Total 32 frags x 64 lanes x 16B = 32 KB; identical for every wave, so
// iterate keeps ONE LDS copy per block instead of 128 AGPRs per wave.
// ---------------------------------------------------------------------------
__global__ void prep_w_kernel(const float* __restrict__ wff,
                              const float* __restrict__ wrec,
                              __bf16* __restrict__ wt,
                              __bf16* __restrict__ wrp) {
  int i = blockIdx.x * 256 + threadIdx.x;
  const int NW = 9 * COUT * CIN;            // 73728
  if (i < NW) {
    int tap = i / (COUT * CIN);
    int rem = i % (COUT * CIN);
    int o = rem >> 6;
    int c = rem & 63;
    int kh = tap / 3, kw = tap % 3;
    wt[i] = (__bf16)wff[((o * CIN + c) * 3 + kh) * 3 + kw];
  } else {
    int j = i - NW;                         // 0..16383
    if (j < 32 * 64 * 8) {
      int e    = j & 7;
      int lane = (j >> 3) & 63;
      int fk   = j >> 9;                    // mt*4 + kt
      int mt = fk >> 2, kt = fk & 3;
      int m    = mt * 16 + (lane & 15);
      int quad = lane >> 4;
      int ch   = kt * 16 + ((e >> 2) << 6) + quad * 4 + (e & 3);
      wrp[j] = (__bf16)(-wrec[m * COUT + ch]);
    }
  }
}

// ---------------------------------------------------------------------------
// prep_x: x NCHW fp32 -> bf16, layout [b][h][c>>3][w][c&7]
// ---------------------------------------------------------------------------
__global__ void prep_x_kernel(const float* __restrict__ x,
                              __bf16* __restrict__ xh) {
  __shared__ float t[64][65];
  int tid = threadIdx.x;
  int b = blockIdx.x >> 6;
  int h = blockIdx.x & 63;
#pragma unroll
  for (int it = 0; it < 16; ++it) {
    int c = it * 4 + (tid >> 6);
    int w = tid & 63;
    t[c][w] = x[(((size_t)(b * 64 + c)) * 64 + h) * 64 + w];
  }
  __syncthreads();
  size_t rowbase = (size_t)blockIdx.x * 4096;
#pragma unroll
  for (int it = 0; it < 16; ++it) {
    int j = it * 256 + tid;
    int c8  = j & 7;
    int w   = (j >> 3) & 63;
    int grp = j >> 9;
    xh[rowbase + j] = (__bf16)t[grp * 8 + c8][w];
  }
}

// ---------------------------------------------------------------------------
// conv: persistent-weight implicit GEMM, 32x32x16 bf16 MFMA.
// Wf (144 regs) pinned into AGPRs -> zero weight traffic in the nt loop.
// ---------------------------------------------------------------------------
__global__ __launch_bounds__(256, 2) void conv_kernel(
    const __bf16* __restrict__ xh, const __bf16* __restrict__ wt,
    float* __restrict__ u0) {
  // layout [row 6][grp 8][w 64][c8 8] = 24576 el = 48KB, flat == global order
  __shared__ __align__(16) __bf16 xs[6 * 8 * 64 * 8];
  int tid  = threadIdx.x;
  int lane = tid & 63;
  int wv   = tid >> 6;                      // 0..3 : c_out slice
  int hg   = blockIdx.x;                    // 0..15 : output-row group (4 rows)
  int b    = blockIdx.y;

  // ---- stage 6 input rows (hg*4 .. hg*4+5, clamped) ----
#pragma unroll
  for (int i = 0; i < 12; ++i) {
    int chunk = wv * 12 + i;                // 0..47
    int row = chunk >> 3;
    int part = chunk & 7;
    int row_src = hg * 4 + row;
    if (row_src > 63) row_src = 63;
    const __bf16* g = xh + ((size_t)(b * 64 + row_src)) * 4096 + part * 512 + lane * 8;
    __bf16* l = xs + chunk * 512;
    __builtin_amdgcn_global_load_lds(
        (const __attribute__((address_space(1))) void*)g,
        (__attribute__((address_space(3))) void*)l, 16, 0, 0);
  }

  // ---- this wave's full weight set -> AGPRs (loaded once, resident) ----
  int m31 = lane & 31;
  int khalf = lane >> 5;                    // A[m][k]: m=lane&31, k=khalf*8+j
  bf16x8 Wf[36];
#pragma unroll
  for (int tap = 0; tap < 9; ++tap)
#pragma unroll
    for (int k4 = 0; k4 < 4; ++k4)
      Wf[tap * 4 + k4] = *(const bf16x8*)
          &wt[((size_t)tap * COUT + wv * 32 + m31) * CIN + k4 * 16 + khalf * 8];
#pragma unroll
  for (int i = 0; i < 36; ++i) PIN_A(Wf[i]);

  __syncthreads();

  // ---- 8 n-tiles of 32 pixels ----
#pragma unroll 1
  for (int nt = 0; nt < 8; ++nt) {
    int px = nt * 32 + m31;                 // local pixel 0..255 (248 valid)
    int r = (px >= 62) + (px >= 124) + (px >= 186) + (px >= 248);
    if (r > 3) r = 3;
    int wcol = px - r * 62;
    if (wcol > 61) wcol = 61;
    int orow = hg * 4 + r;
    bool valid = (px < 248) && (orow < 62);
    const char* lbase = (const char*)xs + (((r * 8 + khalf) * 64 + wcol) << 4);

    f32x16 acc0, acc1;
#pragma unroll
    for (int q = 0; q < 16; ++q) { acc0[q] = 0.f; acc1[q] = 0.f; }

#pragma unroll
    for (int tap = 0; tap < 9; ++tap) {
      int kh = tap / 3, kw = tap % 3;
#pragma unroll
      for (int k4 = 0; k4 < 4; ++k4) {
        bf16x8 Bf = *(const bf16x8*)(lbase + kh * 8192 + k4 * 2048 + kw * 16);
        int idx = tap * 4 + k4;
        if (idx & 1) acc1 = __builtin_amdgcn_mfma_f32_32x32x16_bf16(Wf[idx], Bf, acc1, 0, 0, 0);
        else         acc0 = __builtin_amdgcn_mfma_f32_32x32x16_bf16(Wf[idx], Bf, acc0, 0, 0, 0);
      }
    }
    if (valid) {
      size_t pix = ((size_t)b * HO + orow) * WO + wcol;
      // C/D layout 32x32: col=lane&31, row=(reg&3)+8*(reg>>2)+4*khalf
      float* up = u0 + pix * COUT + wv * 32 + khalf * 4;
#pragma unroll
      for (int g4 = 0; g4 < 4; ++g4) {
        f32x4 v;
#pragma unroll
        for (int q = 0; q < 4; ++q) v[q] = acc0[g4 * 4 + q] + acc1[g4 * 4 + q];
        *(f32x4*)&up[g4 * 8] = v;
      }
    }
  }
}

// ---------------------------------------------------------------------------
// iterate: 11 undamped Picard matvecs. Wave owns M=128 x N=16 pixels.
// A-fragments (identical for every wave) live in ONE 32 KB LDS copy per
// block, ds_read_b128 at use (lane-stride-16B contiguous, conflict-free,
// wave-uniform base + immediate offsets). Repack stays in-register
// (k-permutation). R2 post-mortem: __launch_bounds__(256,4) = 128-reg
// budget forced inner-loop scratch spills (FETCH 62MB -> 1.66GB, 3.5x
// slower). Live values ~110 regs -> need the 3-waves/SIMD budget (170).
// ---------------------------------------------------------------------------
__global__ __launch_bounds__(256, 3) void iterate_kernel(
    const float* __restrict__ u0, const __bf16* __restrict__ wrp,
    const float* __restrict__ thr, float* __restrict__ out) {
  __shared__ __align__(16) __bf16 wrl[32 * 64 * 8];   // 32 KB shared A-table
  int tid = threadIdx.x;
  int lane = tid & 63, wv = tid >> 6;
  int l15 = lane & 15, quad = lane >> 4;
  size_t p = (size_t)blockIdx.x * 64 + wv * 16 + l15; // this lane's pixel
  int pb = (int)(p / (HO * WO));            // batch  (for NCHW store)
  int pr = (int)(p % (HO * WO));            // h*62+w

  // ---- stage wrp -> LDS (8 x 16B per thread, linear both sides) ----
#pragma unroll
  for (int i = 0; i < 8; ++i) {
    const __bf16* g = wrp + (size_t)(i * 256 + tid) * 8;
    __bf16* l = wrl + (i * 256 + tid) * 8;
    __builtin_amdgcn_global_load_lds(
        (const __attribute__((address_space(1))) void*)g,
        (__attribute__((address_space(3))) void*)l, 16, 0, 0);
  }

  // u0 - thr fragments (C-layout), VGPR-resident
  f32x4 u0f[8];
#pragma unroll
  for (int mt = 0; mt < 8; ++mt) {
    f32x4 u = *(const f32x4*)&u0[p * COUT + mt * 16 + quad * 4];
    f32x4 t = *(const f32x4*)&thr[mt * 16 + quad * 4];
    u0f[mt] = u - t;
  }
#pragma unroll
  for (int mt = 0; mt < 8; ++mt) PIN_V(u0f[mt]);

  // acc starts as u0-thr so the first repack yields a_0 = relu(u0-thr)
  f32x4 acc[8];
#pragma unroll
  for (int mt = 0; mt < 8; ++mt) acc[mt] = u0f[mt];

  __syncthreads();                          // wrl ready (vmcnt drained here)

  const __bf16* afrag = &wrl[(size_t)lane * 8];   // + fk*1024B immediates

  bf16x8 Bf[4];
#pragma unroll 1
  for (int it = 0; it < NITER; ++it) {
    // repack: B-slot (kt, q, e) <- relu(acc channel kt*16+64*(e>>2)+q*4+(e&3))
    //         = relu(acc[kt + 4*(e>>2)][e&3])   (purely lane-local)
#pragma unroll
    for (int kt = 0; kt < 4; ++kt) {
      bf16x8 v;
#pragma unroll
      for (int e = 0; e < 4; ++e) v[e]     = (__bf16)fmaxf(acc[kt][e],     0.f);
#pragma unroll
      for (int e = 0; e < 4; ++e) v[e + 4] = (__bf16)fmaxf(acc[kt + 4][e], 0.f);
      Bf[kt] = v;
    }
#pragma unroll
    for (int mt = 0; mt < 8; ++mt) {
      f32x4 a = u0f[mt];                    // acc init = u0-thr; Wr negated
#pragma unroll
      for (int kt = 0; kt < 4; ++kt) {
        bf16x8 Af = *(const bf16x8*)(afrag + (size_t)(mt * 4 + kt) * 512);
        a = __builtin_amdgcn_mfma_f32_16x16x32_bf16(Af, Bf[kt], a, 0, 0, 0);
      }
      acc[mt] = a;
    }
  }
  // final matvec -> relu -> NCHW global store
  {
#pragma unroll
    for (int kt = 0; kt < 4; ++kt) {
      bf16x8 v;
#pragma unroll
      for (int e = 0; e < 4; ++e) v[e]     = (__bf16)fmaxf(acc[kt][e],     0.f);
#pragma unroll
      for (int e = 0; e < 4; ++e) v[e + 4] = (__bf16)fmaxf(acc[kt + 4][e], 0.f);
      Bf[kt] = v;
    }
#pragma unroll
    for (int mt = 0; mt < 8; ++mt) {
      f32x4 a = u0f[mt];
#pragma unroll
      for (int kt = 0; kt < 4; ++kt) {
        bf16x8 Af = *(const bf16x8*)(afrag + (size_t)(mt * 4 + kt) * 512);
        a = __builtin_amdgcn_mfma_f32_16x16x32_bf16(Af, Bf[kt], a, 0, 0, 0);
      }
#pragma unroll
      for (int r = 0; r < 4; ++r) {
        int ch = mt * 16 + quad * 4 + r;
        out[((size_t)pb * COUT + ch) * (HO * WO) + pr] = fmaxf(a[r], 0.f);
      }
    }
  }
}

// ---------------------------------------------------------------------------
extern "C" void kernel_launch(void* const* d_in, const int* in_sizes, int n_in,
                              void* d_out, int out_size, void* d_ws, size_t ws_size,
                              hipStream_t stream) {
  const float* x    = (const float*)d_in[0];   // (64,64,64,64)
  const float* wff  = (const float*)d_in[1];   // (128,64,3,3)
  const float* wrec = (const float*)d_in[2];   // (128,128,1,1)
  const float* thr  = (const float*)d_in[3];   // (128,)
  float* out = (float*)d_out;                  // (64,128,62,62)

  char* ws = (char*)d_ws;
  size_t off = 0;
  float*  u0 = (float*)(ws + off);  off += (size_t)NPIX * COUT * 4;          // 126 MB
  __bf16* xh = (__bf16*)(ws + off); off += (size_t)B_ * HIN * WIN * CIN * 2; // 33.6 MB
  __bf16* wt = (__bf16*)(ws + off); off += (size_t)9 * COUT * CIN * 2;       // 147 KB
  __bf16* wrp = (__bf16*)(ws + off); off += (size_t)32 * 64 * 8 * 2;         // 32 KB

  prep_w_kernel<<<352, 256, 0, stream>>>(wff, wrec, wt, wrp);
  prep_x_kernel<<<B_ * HIN, 256, 0, stream>>>(x, xh);
  conv_kernel<<<dim3(16, B_), 256, 0, stream>>>(xh, wt, u0);
  iterate_kernel<<<NPIX / 64, 256, 0, stream>>>(u0, wrp, thr, out);
}

// Round 4
// 326.683 us; speedup vs baseline: 2.3817x; 1.5952x over previous
//
#include <hip/hip_runtime.h>
#include <hip/hip_bf16.h>

typedef __bf16 bf16x8 __attribute__((ext_vector_type(8)));
typedef __bf16 bf16x4 __attribute__((ext_vector_type(4)));
typedef float  f32x4  __attribute__((ext_vector_type(4)));
typedef float  f32x16 __attribute__((ext_vector_type(16)));

#define B_    64
#define CIN   64
#define HIN   64
#define WIN   64
#define COUT  128
#define HO    62
#define WO    62
#define NPIX  (B_*HO*WO)        /* 246016 = 3844*64 exactly */
#define NITER 10                /* register rounds; +1 final matvec = 11 total */

// Register-file steering. gfx950 has a unified VGPR/AGPR file that the
// compiler splits when launch_bounds caps the budget; "+a" pins a value
// into the AGPR half (native for MFMA C/D), "+v" into the arch half.
#define PIN_A(x) asm volatile("" : "+a"(x))
#define PIN_V(x) asm volatile("" : "+v"(x))

// ---------------------------------------------------------------------------
// prep_w: W_ff -> wt[tap][o][c] bf16 ;
//         W_rec -> wrp: NEGATED, pre-permuted per-lane A-fragment table.
// wrp[((mt*4+kt)*64 + lane)*8 + e] = -wrec[m][ch],
//   m  = mt*16 + (lane&15)
//   ch = kt*16 + 64*(e>>2) + (lane>>4)*4 + (e&3)   (k-slot permutation)
// Total 32 frags x 64 lanes x 16B = 32 KB; identical for every wave, so
// iterate keeps ONE LDS copy per block instead of 128 AGPRs per wave.
// ---------------------------------------------------------------------------
__global__ void prep_w_kernel(const float* __restrict__ wff,
                              const float* __restrict__ wrec,
                              __bf16* __restrict__ wt,
                              __bf16* __restrict__ wrp) {
  int i = blockIdx.x * 256 + threadIdx.x;
  const int NW = 9 * COUT * CIN;            // 73728
  if (i < NW) {
    int tap = i / (COUT * CIN);
    int rem = i % (COUT * CIN);
    int o = rem >> 6;
    int c = rem & 63;
    int kh = tap / 3, kw = tap % 3;
    wt[i] = (__bf16)wff[((o * CIN + c) * 3 + kh) * 3 + kw];
  } else {
    int j = i - NW;                         // 0..16383
    if (j < 32 * 64 * 8) {
      int e    = j & 7;
      int lane = (j >> 3) & 63;
      int fk   = j >> 9;                    // mt*4 + kt
      int mt = fk >> 2, kt = fk & 3;
      int m    = mt * 16 + (lane & 15);
      int quad = lane >> 4;
      int ch   = kt * 16 + ((e >> 2) << 6) + quad * 4 + (e & 3);
      wrp[j] = (__bf16)(-wrec[m * COUT + ch]);
    }
  }
}

// ---------------------------------------------------------------------------
// prep_x: x NCHW fp32 -> bf16, layout [b][h][c>>3][w][c&7]
// ---------------------------------------------------------------------------
__global__ void prep_x_kernel(const float* __restrict__ x,
                              __bf16* __restrict__ xh) {
  __shared__ float t[64][65];
  int tid = threadIdx.x;
  int b = blockIdx.x >> 6;
  int h = blockIdx.x & 63;
#pragma unroll
  for (int it = 0; it < 16; ++it) {
    int c = it * 4 + (tid >> 6);
    int w = tid & 63;
    t[c][w] = x[(((size_t)(b * 64 + c)) * 64 + h) * 64 + w];
  }
  __syncthreads();
  size_t rowbase = (size_t)blockIdx.x * 4096;
#pragma unroll
  for (int it = 0; it < 16; ++it) {
    int j = it * 256 + tid;
    int c8  = j & 7;
    int w   = (j >> 3) & 63;
    int grp = j >> 9;
    xh[rowbase + j] = (__bf16)t[grp * 8 + c8][w];
  }
}

// ---------------------------------------------------------------------------
// conv: persistent-weight implicit GEMM, 32x32x16 bf16 MFMA.
// Wf (144 regs) pinned into AGPRs -> zero weight traffic in the nt loop.
// ---------------------------------------------------------------------------
__global__ __launch_bounds__(256, 2) void conv_kernel(
    const __bf16* __restrict__ xh, const __bf16* __restrict__ wt,
    float* __restrict__ u0) {
  // layout [row 6][grp 8][w 64][c8 8] = 24576 el = 48KB, flat == global order
  __shared__ __align__(16) __bf16 xs[6 * 8 * 64 * 8];
  int tid  = threadIdx.x;
  int lane = tid & 63;
  int wv   = tid >> 6;                      // 0..3 : c_out slice
  int hg   = blockIdx.x;                    // 0..15 : output-row group (4 rows)
  int b    = blockIdx.y;

  // ---- stage 6 input rows (hg*4 .. hg*4+5, clamped) ----
#pragma unroll
  for (int i = 0; i < 12; ++i) {
    int chunk = wv * 12 + i;                // 0..47
    int row = chunk >> 3;
    int part = chunk & 7;
    int row_src = hg * 4 + row;
    if (row_src > 63) row_src = 63;
    const __bf16* g = xh + ((size_t)(b * 64 + row_src)) * 4096 + part * 512 + lane * 8;
    __bf16* l = xs + chunk * 512;
    __builtin_amdgcn_global_load_lds(
        (const __attribute__((address_space(1))) void*)g,
        (__attribute__((address_space(3))) void*)l, 16, 0, 0);
  }

  // ---- this wave's full weight set -> AGPRs (loaded once, resident) ----
  int m31 = lane & 31;
  int khalf = lane >> 5;                    // A[m][k]: m=lane&31, k=khalf*8+j
  bf16x8 Wf[36];
#pragma unroll
  for (int tap = 0; tap < 9; ++tap)
#pragma unroll
    for (int k4 = 0; k4 < 4; ++k4)
      Wf[tap * 4 + k4] = *(const bf16x8*)
          &wt[((size_t)tap * COUT + wv * 32 + m31) * CIN + k4 * 16 + khalf * 8];
#pragma unroll
  for (int i = 0; i < 36; ++i) PIN_A(Wf[i]);

  __syncthreads();

  // ---- 8 n-tiles of 32 pixels ----
#pragma unroll 1
  for (int nt = 0; nt < 8; ++nt) {
    int px = nt * 32 + m31;                 // local pixel 0..255 (248 valid)
    int r = (px >= 62) + (px >= 124) + (px >= 186) + (px >= 248);
    if (r > 3) r = 3;
    int wcol = px - r * 62;
    if (wcol > 61) wcol = 61;
    int orow = hg * 4 + r;
    bool valid = (px < 248) && (orow < 62);
    const char* lbase = (const char*)xs + (((r * 8 + khalf) * 64 + wcol) << 4);

    f32x16 acc0, acc1;
#pragma unroll
    for (int q = 0; q < 16; ++q) { acc0[q] = 0.f; acc1[q] = 0.f; }

#pragma unroll
    for (int tap = 0; tap < 9; ++tap) {
      int kh = tap / 3, kw = tap % 3;
#pragma unroll
      for (int k4 = 0; k4 < 4; ++k4) {
        bf16x8 Bf = *(const bf16x8*)(lbase + kh * 8192 + k4 * 2048 + kw * 16);
        int idx = tap * 4 + k4;
        if (idx & 1) acc1 = __builtin_amdgcn_mfma_f32_32x32x16_bf16(Wf[idx], Bf, acc1, 0, 0, 0);
        else         acc0 = __builtin_amdgcn_mfma_f32_32x32x16_bf16(Wf[idx], Bf, acc0, 0, 0, 0);
      }
    }
    if (valid) {
      size_t pix = ((size_t)b * HO + orow) * WO + wcol;
      // C/D layout 32x32: col=lane&31, row=(reg&3)+8*(reg>>2)+4*khalf
      float* up = u0 + pix * COUT + wv * 32 + khalf * 4;
#pragma unroll
      for (int g4 = 0; g4 < 4; ++g4) {
        f32x4 v;
#pragma unroll
        for (int q = 0; q < 4; ++q) v[q] = acc0[g4 * 4 + q] + acc1[g4 * 4 + q];
        *(f32x4*)&up[g4 * 8] = v;
      }
    }
  }
}

// ---------------------------------------------------------------------------
// iterate: 11 undamped Picard matvecs. Wave owns M=128 x N=16 pixels.
// A-fragments (identical for every wave) live in ONE 32 KB LDS copy per
// block, ds_read_b128 at use. R3 post-mortem: at __launch_bounds__(256,3)
// the 168-reg budget splits 84 arch + 84 AGPR; PIN_V had forced u0f into
// the arch half -> arch overflow -> ~50 regs scratch-spilled (FETCH 592MB).
// Fix: steer acc (32) and u0f (32) into the AGPR half ("+a") -- MFMA
// reads C / writes D there natively, and VALU can source AGPRs for the
// repack. Arch half then holds only Bf + transient Af + addressing (~60).
// ---------------------------------------------------------------------------
__global__ __launch_bounds__(256, 3) void iterate_kernel(
    const float* __restrict__ u0, const __bf16* __restrict__ wrp,
    const float* __restrict__ thr, float* __restrict__ out) {
  __shared__ __align__(16) __bf16 wrl[32 * 64 * 8];   // 32 KB shared A-table
  int tid = threadIdx.x;
  int lane = tid & 63, wv = tid >> 6;
  int l15 = lane & 15, quad = lane >> 4;
  size_t p = (size_t)blockIdx.x * 64 + wv * 16 + l15; // this lane's pixel
  int pb = (int)(p / (HO * WO));            // batch  (for NCHW store)
  int pr = (int)(p % (HO * WO));            // h*62+w

  // ---- stage wrp -> LDS (8 x 16B per thread, linear both sides) ----
#pragma unroll
  for (int i = 0; i < 8; ++i) {
    const __bf16* g = wrp + (size_t)(i * 256 + tid) * 8;
    __bf16* l = wrl + (i * 256 + tid) * 8;
    __builtin_amdgcn_global_load_lds(
        (const __attribute__((address_space(1))) void*)g,
        (__attribute__((address_space(3))) void*)l, 16, 0, 0);
  }

  // u0 - thr fragments (C-layout) -> AGPR half
  f32x4 u0f[8];
#pragma unroll
  for (int mt = 0; mt < 8; ++mt) {
    f32x4 u = *(const f32x4*)&u0[p * COUT + mt * 16 + quad * 4];
    f32x4 t = *(const f32x4*)&thr[mt * 16 + quad * 4];
    u0f[mt] = u - t;
  }
#pragma unroll
  for (int mt = 0; mt < 8; ++mt) PIN_A(u0f[mt]);

  // acc starts as u0-thr so the first repack yields a_0 = relu(u0-thr)
  f32x4 acc[8];
#pragma unroll
  for (int mt = 0; mt < 8; ++mt) { acc[mt] = u0f[mt]; PIN_A(acc[mt]); }

  __syncthreads();                          // wrl ready (vmcnt drained here)

  const __bf16* afrag = &wrl[(size_t)lane * 8];   // + fk*1024B immediates

  bf16x8 Bf[4];
#pragma unroll 1
  for (int it = 0; it < NITER; ++it) {
    // repack: B-slot (kt, q, e) <- relu(acc channel kt*16+64*(e>>2)+q*4+(e&3))
    //         = relu(acc[kt + 4*(e>>2)][e&3])   (purely lane-local)
#pragma unroll
    for (int kt = 0; kt < 4; ++kt) {
      bf16x8 v;
#pragma unroll
      for (int e = 0; e < 4; ++e) v[e]     = (__bf16)fmaxf(acc[kt][e],     0.f);
#pragma unroll
      for (int e = 0; e < 4; ++e) v[e + 4] = (__bf16)fmaxf(acc[kt + 4][e], 0.f);
      Bf[kt] = v;
    }
#pragma unroll
    for (int mt = 0; mt < 8; ++mt) {
      f32x4 a = u0f[mt];                    // acc init = u0-thr; Wr negated
#pragma unroll
      for (int kt = 0; kt < 4; ++kt) {
        bf16x8 Af = *(const bf16x8*)(afrag + (size_t)(mt * 4 + kt) * 512);
        a = __builtin_amdgcn_mfma_f32_16x16x32_bf16(Af, Bf[kt], a, 0, 0, 0);
      }
      acc[mt] = a;
      PIN_A(acc[mt]);                       // keep in AGPR half across iters
    }
  }
  // final matvec -> relu -> NCHW global store
  {
#pragma unroll
    for (int kt = 0; kt < 4; ++kt) {
      bf16x8 v;
#pragma unroll
      for (int e = 0; e < 4; ++e) v[e]     = (__bf16)fmaxf(acc[kt][e],     0.f);
#pragma unroll
      for (int e = 0; e < 4; ++e) v[e + 4] = (__bf16)fmaxf(acc[kt + 4][e], 0.f);
      Bf[kt] = v;
    }
#pragma unroll
    for (int mt = 0; mt < 8; ++mt) {
      f32x4 a = u0f[mt];
#pragma unroll
      for (int kt = 0; kt < 4; ++kt) {
        bf16x8 Af = *(const bf16x8*)(afrag + (size_t)(mt * 4 + kt) * 512);
        a = __builtin_amdgcn_mfma_f32_16x16x32_bf16(Af, Bf[kt], a, 0, 0, 0);
      }
#pragma unroll
      for (int r = 0; r < 4; ++r) {
        int ch = mt * 16 + quad * 4 + r;
        out[((size_t)pb * COUT + ch) * (HO * WO) + pr] = fmaxf(a[r], 0.f);
      }
    }
  }
}

// ---------------------------------------------------------------------------
extern "C" void kernel_launch(void* const* d_in, const int* in_sizes, int n_in,
                              void* d_out, int out_size, void* d_ws, size_t ws_size,
                              hipStream_t stream) {
  const float* x    = (const float*)d_in[0];   // (64,64,64,64)
  const float* wff  = (const float*)d_in[1];   // (128,64,3,3)
  const float* wrec = (const float*)d_in[2];   // (128,128,1,1)
  const float* thr  = (const float*)d_in[3];   // (128,)
  float* out = (float*)d_out;                  // (64,128,62,62)

  char* ws = (char*)d_ws;
  size_t off = 0;
  float*  u0 = (float*)(ws + off);  off += (size_t)NPIX * COUT * 4;          // 126 MB
  __bf16* xh = (__bf16*)(ws + off); off += (size_t)B_ * HIN * WIN * CIN * 2; // 33.6 MB
  __bf16* wt = (__bf16*)(ws + off); off += (size_t)9 * COUT * CIN * 2;       // 147 KB
  __bf16* wrp = (__bf16*)(ws + off); off += (size_t)32 * 64 * 8 * 2;         // 32 KB

  prep_w_kernel<<<352, 256, 0, stream>>>(wff, wrec, wt, wrp);
  prep_x_kernel<<<B_ * HIN, 256, 0, stream>>>(x, xh);
  conv_kernel<<<dim3(16, B_), 256, 0, stream>>>(xh, wt, u0);
  iterate_kernel<<<NPIX / 64, 256, 0, stream>>>(u0, wrp, thr, out);
}

// Round 5
// 325.073 us; speedup vs baseline: 2.3935x; 1.0050x over previous
//
#include <hip/hip_runtime.h>
#include <hip/hip_bf16.h>

typedef __bf16 bf16x8 __attribute__((ext_vector_type(8)));
typedef __bf16 bf16x4 __attribute__((ext_vector_type(4)));
typedef float  f32x4  __attribute__((ext_vector_type(4)));
typedef float  f32x16 __attribute__((ext_vector_type(16)));

#define B_    64
#define CIN   64
#define HIN   64
#define WIN   64
#define COUT  128
#define HO    62
#define WO    62
#define NPIX  (B_*HO*WO)        /* 246016 = 1922*128 exactly */
#define NITER 10                /* register rounds; +1 final matvec = 11 total */

// Register-file steering. gfx950 has a unified VGPR/AGPR file that the
// compiler splits when launch_bounds caps the budget; "+a" pins a value
// into the AGPR half (native for MFMA C/D), "+v" into the arch half.
#define PIN_A(x) asm volatile("" : "+a"(x))
#define PIN_V(x) asm volatile("" : "+v"(x))

// ---------------------------------------------------------------------------
// prep_w: W_ff -> wt[tap][o][c] bf16 ;
//         W_rec -> wrp: NEGATED, pre-permuted per-lane A-fragment table.
// wrp[((mt*4+kt)*64 + lane)*8 + e] = -wrec[m][ch],
//   m  = mt*16 + (lane&15)
//   ch = kt*16 + 64*(e>>2) + (lane>>4)*4 + (e&3)   (k-slot permutation)
// Total 32 frags x 64 lanes x 16B = 32 KB; identical for every wave, so
// iterate keeps ONE LDS copy per block instead of 128 AGPRs per wave.
// ---------------------------------------------------------------------------
__global__ void prep_w_kernel(const float* __restrict__ wff,
                              const float* __restrict__ wrec,
                              __bf16* __restrict__ wt,
                              __bf16* __restrict__ wrp) {
  int i = blockIdx.x * 256 + threadIdx.x;
  const int NW = 9 * COUT * CIN;            // 73728
  if (i < NW) {
    int tap = i / (COUT * CIN);
    int rem = i % (COUT * CIN);
    int o = rem >> 6;
    int c = rem & 63;
    int kh = tap / 3, kw = tap % 3;
    wt[i] = (__bf16)wff[((o * CIN + c) * 3 + kh) * 3 + kw];
  } else {
    int j = i - NW;                         // 0..16383
    if (j < 32 * 64 * 8) {
      int e    = j & 7;
      int lane = (j >> 3) & 63;
      int fk   = j >> 9;                    // mt*4 + kt
      int mt = fk >> 2, kt = fk & 3;
      int m    = mt * 16 + (lane & 15);
      int quad = lane >> 4;
      int ch   = kt * 16 + ((e >> 2) << 6) + quad * 4 + (e & 3);
      wrp[j] = (__bf16)(-wrec[m * COUT + ch]);
    }
  }
}

// ---------------------------------------------------------------------------
// prep_x: x NCHW fp32 -> bf16, layout [b][h][c>>3][w][c&7]
// ---------------------------------------------------------------------------
__global__ void prep_x_kernel(const float* __restrict__ x,
                              __bf16* __restrict__ xh) {
  __shared__ float t[64][65];
  int tid = threadIdx.x;
  int b = blockIdx.x >> 6;
  int h = blockIdx.x & 63;
#pragma unroll
  for (int it = 0; it < 16; ++it) {
    int c = it * 4 + (tid >> 6);
    int w = tid & 63;
    t[c][w] = x[(((size_t)(b * 64 + c)) * 64 + h) * 64 + w];
  }
  __syncthreads();
  size_t rowbase = (size_t)blockIdx.x * 4096;
#pragma unroll
  for (int it = 0; it < 16; ++it) {
    int j = it * 256 + tid;
    int c8  = j & 7;
    int w   = (j >> 3) & 63;
    int grp = j >> 9;
    xh[rowbase + j] = (__bf16)t[grp * 8 + c8][w];
  }
}

// ---------------------------------------------------------------------------
// conv: persistent-weight implicit GEMM, 32x32x16 bf16 MFMA.
// Wf (144 regs) pinned into AGPRs -> zero weight traffic in the nt loop.
// ---------------------------------------------------------------------------
__global__ __launch_bounds__(256, 2) void conv_kernel(
    const __bf16* __restrict__ xh, const __bf16* __restrict__ wt,
    float* __restrict__ u0) {
  // layout [row 6][grp 8][w 64][c8 8] = 24576 el = 48KB, flat == global order
  __shared__ __align__(16) __bf16 xs[6 * 8 * 64 * 8];
  int tid  = threadIdx.x;
  int lane = tid & 63;
  int wv   = tid >> 6;                      // 0..3 : c_out slice
  int hg   = blockIdx.x;                    // 0..15 : output-row group (4 rows)
  int b    = blockIdx.y;

  // ---- stage 6 input rows (hg*4 .. hg*4+5, clamped) ----
#pragma unroll
  for (int i = 0; i < 12; ++i) {
    int chunk = wv * 12 + i;                // 0..47
    int row = chunk >> 3;
    int part = chunk & 7;
    int row_src = hg * 4 + row;
    if (row_src > 63) row_src = 63;
    const __bf16* g = xh + ((size_t)(b * 64 + row_src)) * 4096 + part * 512 + lane * 8;
    __bf16* l = xs + chunk * 512;
    __builtin_amdgcn_global_load_lds(
        (const __attribute__((address_space(1))) void*)g,
        (__attribute__((address_space(3))) void*)l, 16, 0, 0);
  }

  // ---- this wave's full weight set -> AGPRs (loaded once, resident) ----
  int m31 = lane & 31;
  int khalf = lane >> 5;                    // A[m][k]: m=lane&31, k=khalf*8+j
  bf16x8 Wf[36];
#pragma unroll
  for (int tap = 0; tap < 9; ++tap)
#pragma unroll
    for (int k4 = 0; k4 < 4; ++k4)
      Wf[tap * 4 + k4] = *(const bf16x8*)
          &wt[((size_t)tap * COUT + wv * 32 + m31) * CIN + k4 * 16 + khalf * 8];
#pragma unroll
  for (int i = 0; i < 36; ++i) PIN_A(Wf[i]);

  __syncthreads();

  // ---- 8 n-tiles of 32 pixels ----
#pragma unroll 1
  for (int nt = 0; nt < 8; ++nt) {
    int px = nt * 32 + m31;                 // local pixel 0..255 (248 valid)
    int r = (px >= 62) + (px >= 124) + (px >= 186) + (px >= 248);
    if (r > 3) r = 3;
    int wcol = px - r * 62;
    if (wcol > 61) wcol = 61;
    int orow = hg * 4 + r;
    bool valid = (px < 248) && (orow < 62);
    const char* lbase = (const char*)xs + (((r * 8 + khalf) * 64 + wcol) << 4);

    f32x16 acc0, acc1;
#pragma unroll
    for (int q = 0; q < 16; ++q) { acc0[q] = 0.f; acc1[q] = 0.f; }

#pragma unroll
    for (int tap = 0; tap < 9; ++tap) {
      int kh = tap / 3, kw = tap % 3;
#pragma unroll
      for (int k4 = 0; k4 < 4; ++k4) {
        bf16x8 Bf = *(const bf16x8*)(lbase + kh * 8192 + k4 * 2048 + kw * 16);
        int idx = tap * 4 + k4;
        if (idx & 1) acc1 = __builtin_amdgcn_mfma_f32_32x32x16_bf16(Wf[idx], Bf, acc1, 0, 0, 0);
        else         acc0 = __builtin_amdgcn_mfma_f32_32x32x16_bf16(Wf[idx], Bf, acc0, 0, 0, 0);
      }
    }
    if (valid) {
      size_t pix = ((size_t)b * HO + orow) * WO + wcol;
      // C/D layout 32x32: col=lane&31, row=(reg&3)+8*(reg>>2)+4*khalf
      float* up = u0 + pix * COUT + wv * 32 + khalf * 4;
#pragma unroll
      for (int g4 = 0; g4 < 4; ++g4) {
        f32x4 v;
#pragma unroll
        for (int q = 0; q < 4; ++q) v[q] = acc0[g4 * 4 + q] + acc1[g4 * 4 + q];
        *(f32x4*)&up[g4 * 8] = v;
      }
    }
  }
}

// ---------------------------------------------------------------------------
// iterate: 11 undamped Picard matvecs. R4 post-mortem: at N=16/wave the
// kernel is ds_read-issue-bound -- per SIMD-iter: LDS 3x32x12=1152 cyc vs
// MFMA 3x32x5=480 (measured MfmaUtil 42% = 480/1152, VALUBusy 57% ~
// 600/1152 -- model confirmed). Fix: N=32 pixels/wave (2 B-groups), so
// each Af ds_read feeds TWO MFMAs: per SIMD-iter LDS 768 / MFMA 640 /
// VALU ~500 and 2x pixels per wave. Regs: AGPR acc 64 + u0f 64 = 128;
// arch Bf 32 + transient ~40 => ~198 of 256 @ 2 waves/SIMD (slack ~58,
// no spill). LDS 32KB x 2 blocks/CU.
// ---------------------------------------------------------------------------
__global__ __launch_bounds__(256, 2) void iterate_kernel(
    const float* __restrict__ u0, const __bf16* __restrict__ wrp,
    const float* __restrict__ thr, float* __restrict__ out) {
  __shared__ __align__(16) __bf16 wrl[32 * 64 * 8];   // 32 KB shared A-table
  int tid = threadIdx.x;
  int lane = tid & 63, wv = tid >> 6;
  int l15 = lane & 15, quad = lane >> 4;
  // wave owns 32 pixels: group ng at  block*128 + wv*32 + ng*16 + l15
  size_t p0 = (size_t)blockIdx.x * 128 + wv * 32 + l15;
  size_t p1 = p0 + 16;
  int pb0 = (int)(p0 / (HO * WO)), pr0 = (int)(p0 % (HO * WO));
  int pb1 = (int)(p1 / (HO * WO)), pr1 = (int)(p1 % (HO * WO));

  // ---- stage wrp -> LDS (8 x 16B per thread, linear both sides) ----
#pragma unroll
  for (int i = 0; i < 8; ++i) {
    const __bf16* g = wrp + (size_t)(i * 256 + tid) * 8;
    __bf16* l = wrl + (i * 256 + tid) * 8;
    __builtin_amdgcn_global_load_lds(
        (const __attribute__((address_space(1))) void*)g,
        (__attribute__((address_space(3))) void*)l, 16, 0, 0);
  }

  // u0 - thr fragments (C-layout) -> AGPR half. Two pixel groups.
  f32x4 u0f0[8], u0f1[8];
#pragma unroll
  for (int mt = 0; mt < 8; ++mt) {
    f32x4 t = *(const f32x4*)&thr[mt * 16 + quad * 4];
    f32x4 ua = *(const f32x4*)&u0[p0 * COUT + mt * 16 + quad * 4];
    f32x4 ub = *(const f32x4*)&u0[p1 * COUT + mt * 16 + quad * 4];
    u0f0[mt] = ua - t;
    u0f1[mt] = ub - t;
  }
#pragma unroll
  for (int mt = 0; mt < 8; ++mt) { PIN_A(u0f0[mt]); PIN_A(u0f1[mt]); }

  // acc starts as u0-thr so the first repack yields a_0 = relu(u0-thr)
  f32x4 acc0[8], acc1[8];
#pragma unroll
  for (int mt = 0; mt < 8; ++mt) {
    acc0[mt] = u0f0[mt]; PIN_A(acc0[mt]);
    acc1[mt] = u0f1[mt]; PIN_A(acc1[mt]);
  }

  __syncthreads();                          // wrl ready (vmcnt drained here)

  const __bf16* afrag = &wrl[(size_t)lane * 8];   // + fk*1024B immediates

  bf16x8 Bf0[4], Bf1[4];
#pragma unroll 1
  for (int it = 0; it < NITER; ++it) {
    // repack: B-slot (kt, q, e) <- relu(acc channel kt*16+64*(e>>2)+q*4+(e&3))
    //         = relu(acc[kt + 4*(e>>2)][e&3])   (purely lane-local)
#pragma unroll
    for (int kt = 0; kt < 4; ++kt) {
      bf16x8 v0, v1;
#pragma unroll
      for (int e = 0; e < 4; ++e) {
        v0[e]     = (__bf16)fmaxf(acc0[kt][e],     0.f);
        v0[e + 4] = (__bf16)fmaxf(acc0[kt + 4][e], 0.f);
        v1[e]     = (__bf16)fmaxf(acc1[kt][e],     0.f);
        v1[e + 4] = (__bf16)fmaxf(acc1[kt + 4][e], 0.f);
      }
      Bf0[kt] = v0; Bf1[kt] = v1;
    }
#pragma unroll
    for (int mt = 0; mt < 8; ++mt) {
      f32x4 a0 = u0f0[mt];                  // acc init = u0-thr; Wr negated
      f32x4 a1 = u0f1[mt];
#pragma unroll
      for (int kt = 0; kt < 4; ++kt) {
        bf16x8 Af = *(const bf16x8*)(afrag + (size_t)(mt * 4 + kt) * 512);
        a0 = __builtin_amdgcn_mfma_f32_16x16x32_bf16(Af, Bf0[kt], a0, 0, 0, 0);
        a1 = __builtin_amdgcn_mfma_f32_16x16x32_bf16(Af, Bf1[kt], a1, 0, 0, 0);
      }
      acc0[mt] = a0; PIN_A(acc0[mt]);
      acc1[mt] = a1; PIN_A(acc1[mt]);
    }
  }
  // final matvec -> relu -> NCHW global store
  {
#pragma unroll
    for (int kt = 0; kt < 4; ++kt) {
      bf16x8 v0, v1;
#pragma unroll
      for (int e = 0; e < 4; ++e) {
        v0[e]     = (__bf16)fmaxf(acc0[kt][e],     0.f);
        v0[e + 4] = (__bf16)fmaxf(acc0[kt + 4][e], 0.f);
        v1[e]     = (__bf16)fmaxf(acc1[kt][e],     0.f);
        v1[e + 4] = (__bf16)fmaxf(acc1[kt + 4][e], 0.f);
      }
      Bf0[kt] = v0; Bf1[kt] = v1;
    }
#pragma unroll
    for (int mt = 0; mt < 8; ++mt) {
      f32x4 a0 = u0f0[mt];
      f32x4 a1 = u0f1[mt];
#pragma unroll
      for (int kt = 0; kt < 4; ++kt) {
        bf16x8 Af = *(const bf16x8*)(afrag + (size_t)(mt * 4 + kt) * 512);
        a0 = __builtin_amdgcn_mfma_f32_16x16x32_bf16(Af, Bf0[kt], a0, 0, 0, 0);
        a1 = __builtin_amdgcn_mfma_f32_16x16x32_bf16(Af, Bf1[kt], a1, 0, 0, 0);
      }
#pragma unroll
      for (int r = 0; r < 4; ++r) {
        int ch = mt * 16 + quad * 4 + r;
        out[((size_t)pb0 * COUT + ch) * (HO * WO) + pr0] = fmaxf(a0[r], 0.f);
        out[((size_t)pb1 * COUT + ch) * (HO * WO) + pr1] = fmaxf(a1[r], 0.f);
      }
    }
  }
}

// ---------------------------------------------------------------------------
extern "C" void kernel_launch(void* const* d_in, const int* in_sizes, int n_in,
                              void* d_out, int out_size, void* d_ws, size_t ws_size,
                              hipStream_t stream) {
  const float* x    = (const float*)d_in[0];   // (64,64,64,64)
  const float* wff  = (const float*)d_in[1];   // (128,64,3,3)
  const float* wrec = (const float*)d_in[2];   // (128,128,1,1)
  const float* thr  = (const float*)d_in[3];   // (128,)
  float* out = (float*)d_out;                  // (64,128,62,62)

  char* ws = (char*)d_ws;
  size_t off = 0;
  float*  u0 = (float*)(ws + off);  off += (size_t)NPIX * COUT * 4;          // 126 MB
  __bf16* xh = (__bf16*)(ws + off); off += (size_t)B_ * HIN * WIN * CIN * 2; // 33.6 MB
  __bf16* wt = (__bf16*)(ws + off); off += (size_t)9 * COUT * CIN * 2;       // 147 KB
  __bf16* wrp = (__bf16*)(ws + off); off += (size_t)32 * 64 * 8 * 2;         // 32 KB

  prep_w_kernel<<<352, 256, 0, stream>>>(wff, wrec, wt, wrp);
  prep_x_kernel<<<B_ * HIN, 256, 0, stream>>>(x, xh);
  conv_kernel<<<dim3(16, B_), 256, 0, stream>>>(xh, wt, u0);
  iterate_kernel<<<NPIX / 128, 256, 0, stream>>>(u0, wrp, thr, out);
}